// Round 3
// baseline (2326.174 us; speedup 1.0000x reference)
//
#include <hip/hip_runtime.h>

typedef _Float16 f16;
typedef _Float16 f16x8 __attribute__((ext_vector_type(8)));
typedef float f32x4 __attribute__((ext_vector_type(4)));

#define B_ 4096
#define N_ 32768
#define D_ 1024
#define BM 32
#define BN 256          // KV tile per iteration (32 cols per wave x 8 waves)
#define COLS 32
#define THREADS 512
#define DSLICE 128      // D columns owned per wave in PV
#define NHALF (N_ / 2)
#define ITERS (NHALF / BN)   // 64

__device__ __forceinline__ f32x4 mfma16(f16x8 a, f16x8 b, f32x4 c) {
    return __builtin_amdgcn_mfma_f32_16x16x32_f16(a, b, c, 0, 0, 0);
}

// ---- convert K (fp32 -> f16, same layout) -----------------------------------
__global__ void conv_k16(const float* __restrict__ src, f16* __restrict__ dst) {
    size_t i = ((size_t)blockIdx.x * blockDim.x + threadIdx.x) * 8;
    const float4* s = (const float4*)(src + i);
    float4 a = s[0], b = s[1];
    f16x8 h;
    h[0] = (f16)a.x; h[1] = (f16)a.y; h[2] = (f16)a.z; h[3] = (f16)a.w;
    h[4] = (f16)b.x; h[5] = (f16)b.y; h[6] = (f16)b.z; h[7] = (f16)b.w;
    *(f16x8*)(dst + i) = h;
}

// ---- convert + transpose V: V[N][D] fp32 -> VT[D][N] f16 ---------------------
__global__ void conv_vt(const float* __restrict__ V, f16* __restrict__ VT) {
    __shared__ f16 tile[64][65];
    int n0 = blockIdx.x << 6, d0 = blockIdx.y << 6;
    for (int idx = threadIdx.x; idx < 4096; idx += 256) {
        int i = idx >> 6, j = idx & 63;
        tile[j][i] = (f16)V[(size_t)(n0 + i) * D_ + d0 + j];
    }
    __syncthreads();
    for (int idx = threadIdx.x; idx < 4096; idx += 256) {
        int j = idx >> 6, i = idx & 63;
        VT[(size_t)(d0 + j) * N_ + n0 + i] = tile[j][i];
    }
}

// ---- main fused attention kernel --------------------------------------------
// LDS layouts are "k-major": off(row, d) = (d>>5)*ROWSTRIDE + row*64
//                                        + ((d&31)>>3)*16 + (d&7)*2
// so an MFMA fragment read is base(row,lg) + ks*2048 (immediate only touches
// bits >= 11 -> no swizzle/carry interaction, lane-consecutive 16B = conflict-free).
__global__ __launch_bounds__(THREADS)
void attn_main(const float* __restrict__ Xg, const f16* __restrict__ Kh,
               const f16* __restrict__ VT, float* __restrict__ Opart,
               float* __restrict__ Mpart, float* __restrict__ Lpart)
{
    __shared__ __align__(16) f16 Xhi[BM * D_];   // 64 KB, k-major
    __shared__ __align__(16) f16 Xlo[BM * D_];   // 64 KB, k-major
    __shared__ __align__(16) f16 Pl[BM * BN];    // 16 KB, k-major
    __shared__ float2 red[BM][9];                // [row][wave], pad 9 -> conflict-free

    const int xcd   = blockIdx.x & 7;
    const int chunk = xcd >> 2;                          // N-split half
    const int bblk  = ((blockIdx.x >> 3) << 2) | (xcd & 3);
    const int kvbase = chunk * NHALF;
    const int b0 = bblk * BM;
    const int t  = threadIdx.x;

    // --- stage X: fp32 -> f16 hi/lo into k-major LDS (conflict-free writes) ---
    for (int c = t; c < BM * D_ / 8; c += THREADS) {
        int dblk = c >> 7;            // 0..31 : which 32-wide d block
        int row  = (c >> 2) & 31;
        int sub  = c & 3;             // which 8-wide sub chunk
        int d0   = dblk * 32 + sub * 8;
        const float4* s = (const float4*)(Xg + (size_t)(b0 + row) * D_ + d0);
        float4 a = s[0], b = s[1];
        f16x8 hi, lo;
        hi[0] = (f16)a.x; lo[0] = (f16)(a.x - (float)hi[0]);
        hi[1] = (f16)a.y; lo[1] = (f16)(a.y - (float)hi[1]);
        hi[2] = (f16)a.z; lo[2] = (f16)(a.z - (float)hi[2]);
        hi[3] = (f16)a.w; lo[3] = (f16)(a.w - (float)hi[3]);
        hi[4] = (f16)b.x; lo[4] = (f16)(b.x - (float)hi[4]);
        hi[5] = (f16)b.y; lo[5] = (f16)(b.y - (float)hi[5]);
        hi[6] = (f16)b.z; lo[6] = (f16)(b.z - (float)hi[6]);
        hi[7] = (f16)b.w; lo[7] = (f16)(b.w - (float)hi[7]);
        int off = dblk * 2048 + row * 64 + sub * 16;
        *(f16x8*)((char*)Xhi + off) = hi;
        *(f16x8*)((char*)Xlo + off) = lo;
    }
    __syncthreads();

    const int wave = t >> 6, lane = t & 63;
    const int l15 = lane & 15, lg = lane >> 4;
    const int cw = wave * COLS;

    // LDS read bases; per-ks offsets are pure immediates (multiples of 2048)
    const char* bh0 = (const char*)Xhi + l15 * 64 + lg * 16;
    const char* bh1 = (const char*)Xhi + (l15 + 16) * 64 + lg * 16;
    const char* bl0 = (const char*)Xlo + l15 * 64 + lg * 16;
    const char* bl1 = (const char*)Xlo + (l15 + 16) * 64 + lg * 16;
    const char* pr0 = (const char*)Pl + l15 * 64 + lg * 16;
    const char* pr1 = (const char*)Pl + (l15 + 16) * 64 + lg * 16;

    // global running pointers (advance by BN rows / BN cols per iter)
    const f16* kp0 = Kh + (size_t)(kvbase + cw + l15) * D_ + lg * 8;
    const f16* kp1 = Kh + (size_t)(kvbase + cw + 16 + l15) * D_ + lg * 8;
    const f16* vp[8];
    #pragma unroll
    for (int fn = 0; fn < 8; ++fn)
        vp[fn] = VT + (size_t)(wave * DSLICE + fn * 16 + l15) * N_ + kvbase + lg * 8;

    f32x4 S[2][2];
    auto QK = [&]() {
        #pragma unroll
        for (int rg = 0; rg < 2; ++rg)
            #pragma unroll
            for (int cg = 0; cg < 2; ++cg) S[rg][cg] = (f32x4){0.f, 0.f, 0.f, 0.f};
        #pragma unroll 8
        for (int ks = 0; ks < 32; ++ks) {
            f16x8 k0  = *(const f16x8*)(kp0 + ks * 32);
            f16x8 k1  = *(const f16x8*)(kp1 + ks * 32);
            f16x8 ah0 = *(const f16x8*)(bh0 + ks * 2048);
            f16x8 ah1 = *(const f16x8*)(bh1 + ks * 2048);
            f16x8 al0 = *(const f16x8*)(bl0 + ks * 2048);
            f16x8 al1 = *(const f16x8*)(bl1 + ks * 2048);
            __builtin_amdgcn_s_setprio(1);
            S[0][0] = mfma16(ah0, k0, S[0][0]);
            S[0][1] = mfma16(ah0, k1, S[0][1]);
            S[1][0] = mfma16(ah1, k0, S[1][0]);
            S[1][1] = mfma16(ah1, k1, S[1][1]);
            S[0][0] = mfma16(al0, k0, S[0][0]);
            S[0][1] = mfma16(al0, k1, S[0][1]);
            S[1][0] = mfma16(al1, k0, S[1][0]);
            S[1][1] = mfma16(al1, k1, S[1][1]);
            __builtin_amdgcn_s_setprio(0);
        }
    };

    f32x4 O[2][8];
    #pragma unroll
    for (int rg = 0; rg < 2; ++rg)
        #pragma unroll
        for (int fn = 0; fn < 8; ++fn) O[rg][fn] = (f32x4){0.f, 0.f, 0.f, 0.f};
    float mq[8];
    #pragma unroll
    for (int u = 0; u < 8; ++u) mq[u] = -INFINITY;
    float m2a = -INFINITY, m2b = -INFINITY, l2a = 0.f, l2b = 0.f;

    QK();   // tile 0

    for (int it = 0; it < ITERS; ++it) {
        // ---- strip softmax (own 32 cols): max, exp, sum; publish P + {m,s} ----
        #pragma unroll
        for (int rg = 0; rg < 2; ++rg)
            #pragma unroll
            for (int i = 0; i < 4; ++i) {
                float a = S[rg][0][i], b = S[rg][1][i];
                float mx = fmaxf(a, b);
                mx = fmaxf(mx, __shfl_xor(mx, 1));
                mx = fmaxf(mx, __shfl_xor(mx, 2));
                mx = fmaxf(mx, __shfl_xor(mx, 4));
                mx = fmaxf(mx, __shfl_xor(mx, 8));
                float p0 = __expf(a - mx), p1 = __expf(b - mx);
                float s = p0 + p1;
                s += __shfl_xor(s, 1);
                s += __shfl_xor(s, 2);
                s += __shfl_xor(s, 4);
                s += __shfl_xor(s, 8);
                int m = rg * 16 + lg * 4 + i;
                // k-major: cols cw+l15 and cw+16+l15 both live in block (col>>5)==wave
                int off0 = wave * 2048 + m * 64 + ((l15 >> 3) << 4) + ((l15 & 7) << 1);
                *(f16*)((char*)Pl + off0)      = (f16)p0;
                *(f16*)((char*)Pl + off0 + 32) = (f16)p1;
                if (l15 == 0) red[m][wave] = make_float2(mx, s);
            }
        __syncthreads();

        // ---- combine: global max per row (l15-view), beta per strip, l update ----
        float M2an = m2a, M2bn = m2b;
        #pragma unroll
        for (int s2 = 0; s2 < 8; ++s2) {
            M2an = fmaxf(M2an, red[l15][s2].x);
            M2bn = fmaxf(M2bn, red[l15 + 16][s2].x);
        }
        float ba[8], bb[8];
        float laa = 0.f, lbb = 0.f;
        #pragma unroll
        for (int s2 = 0; s2 < 8; ++s2) {
            float2 ra = red[l15][s2], rb = red[l15 + 16][s2];
            ba[s2] = __expf(ra.x - M2an); laa += ra.y * ba[s2];
            bb[s2] = __expf(rb.x - M2bn); lbb += rb.y * bb[s2];
        }
        l2a = l2a * __expf(m2a - M2an) + laa; m2a = M2an;
        l2b = l2b * __expf(m2b - M2bn) + lbb; m2b = M2bn;

        // ---- q-view alpha via shfl; rescale O ----
        float al[2][4];
        #pragma unroll
        for (int rg = 0; rg < 2; ++rg)
            #pragma unroll
            for (int i = 0; i < 4; ++i) {
                int u = rg * 4 + i;
                int src = (lane & 48) | (lg * 4 + i);
                float Mq = __shfl(rg ? M2bn : M2an, src);
                al[rg][i] = __expf(mq[u] - Mq);
                mq[u] = Mq;
            }
        #pragma unroll
        for (int rg = 0; rg < 2; ++rg)
            #pragma unroll
            for (int fn = 0; fn < 8; ++fn)
                #pragma unroll
                for (int i = 0; i < 4; ++i)
                    O[rg][fn][i] *= al[rg][i];

        // ---- PV: O += (P * beta) x V ----
        #pragma unroll
        for (int ks2 = 0; ks2 < 8; ++ks2) {
            f16 ba16 = (f16)ba[ks2], bb16 = (f16)bb[ks2];
            f16x8 pa0 = *(const f16x8*)(pr0 + ks2 * 2048);
            f16x8 pa1 = *(const f16x8*)(pr1 + ks2 * 2048);
            #pragma unroll
            for (int j = 0; j < 8; ++j) { pa0[j] *= ba16; pa1[j] *= bb16; }
            __builtin_amdgcn_s_setprio(1);
            #pragma unroll
            for (int fn = 0; fn < 8; ++fn) {
                f16x8 v = *(const f16x8*)(vp[fn] + ks2 * 32);
                O[0][fn] = mfma16(pa0, v, O[0][fn]);
                O[1][fn] = mfma16(pa1, v, O[1][fn]);
            }
            __builtin_amdgcn_s_setprio(0);
        }

        // ---- advance, then next tile's QK before the closing barrier ----
        kp0 += (size_t)BN * D_;
        kp1 += (size_t)BN * D_;
        #pragma unroll
        for (int fn = 0; fn < 8; ++fn) vp[fn] += BN;
        if (it + 1 < ITERS) QK();
        __syncthreads();
    }

    // ---- epilogue: unnormalized O + per-row m/l partials ----
    float* Op = Opart + (size_t)chunk * B_ * D_;
    #pragma unroll
    for (int rg = 0; rg < 2; ++rg)
        #pragma unroll
        for (int fn = 0; fn < 8; ++fn)
            #pragma unroll
            for (int i = 0; i < 4; ++i) {
                int row = b0 + rg * 16 + lg * 4 + i;
                int col = wave * DSLICE + fn * 16 + l15;
                Op[(size_t)row * D_ + col] = O[rg][fn][i];
            }
    if (wave == 0 && lg == 0) {
        Mpart[(size_t)chunk * B_ + b0 + l15]      = m2a;
        Lpart[(size_t)chunk * B_ + b0 + l15]      = l2a;
        Mpart[(size_t)chunk * B_ + b0 + 16 + l15] = m2b;
        Lpart[(size_t)chunk * B_ + b0 + 16 + l15] = l2b;
    }
}

// ---- combine NSPLIT=2 partials ----------------------------------------------
__global__ void combine_k(const float* __restrict__ Opart,
                          const float* __restrict__ Mp, const float* __restrict__ Lp,
                          float* __restrict__ Outg)
{
    int b = blockIdx.x;
    float m0 = Mp[b], m1 = Mp[B_ + b];
    float l0 = Lp[b], l1 = Lp[B_ + b];
    float M  = fmaxf(m0, m1);
    float w0 = __expf(m0 - M), w1 = __expf(m1 - M);
    float inv = 1.f / (w0 * l0 + w1 * l1);
    const float4* O0 = (const float4*)(Opart + (size_t)b * D_);
    const float4* O1 = (const float4*)(Opart + (size_t)B_ * D_ + (size_t)b * D_);
    float4* o = (float4*)(Outg + (size_t)b * D_);
    for (int i = threadIdx.x; i < D_ / 4; i += blockDim.x) {
        float4 a = O0[i], c = O1[i];
        float4 r;
        r.x = (w0 * a.x + w1 * c.x) * inv;
        r.y = (w0 * a.y + w1 * c.y) * inv;
        r.z = (w0 * a.z + w1 * c.z) * inv;
        r.w = (w0 * a.w + w1 * c.w) * inv;
        o[i] = r;
    }
}

extern "C" void kernel_launch(void* const* d_in, const int* in_sizes, int n_in,
                              void* d_out, int out_size, void* d_ws, size_t ws_size,
                              hipStream_t stream) {
    const float* X = (const float*)d_in[0];
    const float* K = (const float*)d_in[1];
    const float* V = (const float*)d_in[2];
    float* Out = (float*)d_out;

    const size_t szKh = (size_t)N_ * D_ * sizeof(f16);   // 64 MiB
    const size_t szVT = (size_t)N_ * D_ * sizeof(f16);   // 64 MiB
    const size_t szOp = 2ull * B_ * D_ * sizeof(float);  // 32 MiB
    const size_t szM  = 2ull * B_ * sizeof(float);

    f16*   Kh = (f16*)d_ws;
    f16*   VT = (f16*)((char*)d_ws + szKh);
    float* Op = (float*)((char*)d_ws + szKh + szVT);
    float* Mp = (float*)((char*)Op + szOp);
    float* Lp = (float*)((char*)Mp + szM);

    conv_k16<<<(N_ * D_ / 8) / 256, 256, 0, stream>>>(K, Kh);
    conv_vt<<<dim3(N_ / 64, D_ / 64), 256, 0, stream>>>(V, VT);
    attn_main<<<256, THREADS, 0, stream>>>(X, Kh, VT, Op, Mp, Lp);
    combine_k<<<B_, 256, 0, stream>>>(Op, Mp, Lp, Out);
}

// Round 6
// 2109.247 us; speedup vs baseline: 1.1028x; 1.1028x over previous
//
#include <hip/hip_runtime.h>

typedef _Float16 f16;
typedef _Float16 f16x8 __attribute__((ext_vector_type(8)));
typedef float f32x4 __attribute__((ext_vector_type(4)));

#define B_ 4096
#define N_ 32768
#define D_ 1024
#define BM 32
#define BN 256          // KV tile per iteration (32 cols per wave x 8 waves)
#define COLS 32
#define THREADS 512
#define DSLICE 128      // D columns owned per wave in PV
#define NHALF (N_ / 2)
#define ITERS (NHALF / BN)   // 64

__device__ __forceinline__ f32x4 mfma16(f16x8 a, f16x8 b, f32x4 c) {
    return __builtin_amdgcn_mfma_f32_16x16x32_f16(a, b, c, 0, 0, 0);
}

// ---- convert K (fp32 -> f16, same layout) -----------------------------------
__global__ void conv_k16(const float* __restrict__ src, f16* __restrict__ dst) {
    size_t i = ((size_t)blockIdx.x * blockDim.x + threadIdx.x) * 8;
    const float4* s = (const float4*)(src + i);
    float4 a = s[0], b = s[1];
    f16x8 h;
    h[0] = (f16)a.x; h[1] = (f16)a.y; h[2] = (f16)a.z; h[3] = (f16)a.w;
    h[4] = (f16)b.x; h[5] = (f16)b.y; h[6] = (f16)b.z; h[7] = (f16)b.w;
    *(f16x8*)(dst + i) = h;
}

// ---- convert + transpose V: V[N][D] fp32 -> VT[D][N] f16 ---------------------
__global__ void conv_vt(const float* __restrict__ V, f16* __restrict__ VT) {
    __shared__ f16 tile[64][65];
    int n0 = blockIdx.x << 6, d0 = blockIdx.y << 6;
    for (int idx = threadIdx.x; idx < 4096; idx += 256) {
        int i = idx >> 6, j = idx & 63;
        tile[j][i] = (f16)V[(size_t)(n0 + i) * D_ + d0 + j];
    }
    __syncthreads();
    for (int idx = threadIdx.x; idx < 4096; idx += 256) {
        int j = idx >> 6, i = idx & 63;
        VT[(size_t)(d0 + j) * N_ + n0 + i] = tile[j][i];
    }
}

// ---- main fused attention kernel --------------------------------------------
// k-major LDS: off(row,d) = (d>>5)*2048 + row*64 + ((d&31)>>3)*16 + (d&7)*2
// -> fragment read = base(row,lg) + ks*2048 (imm only touches bits>=11),
//    lane-consecutive 16B, conflict-free, no swizzle math.
__global__ __launch_bounds__(THREADS, 2)
void attn_main(const float* __restrict__ Xg, const f16* __restrict__ Kh,
               const f16* __restrict__ VT, float* __restrict__ Opart,
               float* __restrict__ Mpart, float* __restrict__ Lpart)
{
    __shared__ __align__(16) f16 Xhi[BM * D_];   // 64 KB, k-major
    __shared__ __align__(16) f16 Xlo[BM * D_];   // 64 KB, k-major
    __shared__ __align__(16) f16 Pl[BM * BN];    // 16 KB, k-major
    __shared__ float2 red[BM][9];                // [row][wave], pad -> conflict-free

    const int xcd   = blockIdx.x & 7;
    const int chunk = xcd >> 2;
    const int bblk  = ((blockIdx.x >> 3) << 2) | (xcd & 3);
    const int kvbase = chunk * NHALF;
    const int b0 = bblk * BM;
    const int t  = threadIdx.x;

    // --- stage X: fp32 -> f16 hi/lo into k-major LDS ---
    for (int c = t; c < BM * D_ / 8; c += THREADS) {
        int dblk = c >> 7;
        int row  = (c >> 2) & 31;
        int sub  = c & 3;
        int d0   = dblk * 32 + sub * 8;
        const float4* s = (const float4*)(Xg + (size_t)(b0 + row) * D_ + d0);
        float4 a = s[0], b = s[1];
        f16x8 hi, lo;
        hi[0] = (f16)a.x; lo[0] = (f16)(a.x - (float)hi[0]);
        hi[1] = (f16)a.y; lo[1] = (f16)(a.y - (float)hi[1]);
        hi[2] = (f16)a.z; lo[2] = (f16)(a.z - (float)hi[2]);
        hi[3] = (f16)a.w; lo[3] = (f16)(a.w - (float)hi[3]);
        hi[4] = (f16)b.x; lo[4] = (f16)(b.x - (float)hi[4]);
        hi[5] = (f16)b.y; lo[5] = (f16)(b.y - (float)hi[5]);
        hi[6] = (f16)b.z; lo[6] = (f16)(b.z - (float)hi[6]);
        hi[7] = (f16)b.w; lo[7] = (f16)(b.w - (float)hi[7]);
        int off = dblk * 2048 + row * 64 + sub * 16;
        *(f16x8*)((char*)Xhi + off) = hi;
        *(f16x8*)((char*)Xlo + off) = lo;
    }
    __syncthreads();

    const int wave = t >> 6, lane = t & 63;
    const int l15 = lane & 15, lg = lane >> 4;
    const int cw = wave * COLS;

    const char* bh0 = (const char*)Xhi + l15 * 64 + lg * 16;
    const char* bh1 = (const char*)Xhi + (l15 + 16) * 64 + lg * 16;
    const char* bl0 = (const char*)Xlo + l15 * 64 + lg * 16;
    const char* bl1 = (const char*)Xlo + (l15 + 16) * 64 + lg * 16;
    const char* pr0 = (const char*)Pl + l15 * 64 + lg * 16;
    const char* pr1 = (const char*)Pl + (l15 + 16) * 64 + lg * 16;

    const f16* kp0 = Kh + (size_t)(kvbase + cw + l15) * D_ + lg * 8;
    const f16* kp1 = Kh + (size_t)(kvbase + cw + 16 + l15) * D_ + lg * 8;
    const f16* vp[8];
    #pragma unroll
    for (int fn = 0; fn < 8; ++fn)
        vp[fn] = VT + (size_t)(wave * DSLICE + fn * 16 + l15) * N_ + kvbase + lg * 8;

    f32x4 S[2][2];
    f16x8 kA[8], kB[8];

    auto LOADK = [&](f16x8* buf, int ks0) {
        #pragma unroll
        for (int j = 0; j < 4; ++j) {
            buf[2 * j]     = *(const f16x8*)(kp0 + (ks0 + j) * 32);
            buf[2 * j + 1] = *(const f16x8*)(kp1 + (ks0 + j) * 32);
        }
    };
    auto USEK = [&](const f16x8* kb2, int ks0) {
        #pragma unroll
        for (int j = 0; j < 4; ++j) {
            int ks = ks0 + j;
            f16x8 ah0 = *(const f16x8*)(bh0 + ks * 2048);
            f16x8 ah1 = *(const f16x8*)(bh1 + ks * 2048);
            f16x8 al0 = *(const f16x8*)(bl0 + ks * 2048);
            f16x8 al1 = *(const f16x8*)(bl1 + ks * 2048);
            __builtin_amdgcn_s_setprio(1);
            S[0][0] = mfma16(ah0, kb2[2 * j],     S[0][0]);
            S[0][1] = mfma16(ah0, kb2[2 * j + 1], S[0][1]);
            S[1][0] = mfma16(ah1, kb2[2 * j],     S[1][0]);
            S[1][1] = mfma16(ah1, kb2[2 * j + 1], S[1][1]);
            S[0][0] = mfma16(al0, kb2[2 * j],     S[0][0]);
            S[0][1] = mfma16(al0, kb2[2 * j + 1], S[0][1]);
            S[1][0] = mfma16(al1, kb2[2 * j],     S[1][0]);
            S[1][1] = mfma16(al1, kb2[2 * j + 1], S[1][1]);
            __builtin_amdgcn_s_setprio(0);
        }
    };
    auto QK = [&]() {
        #pragma unroll
        for (int rg = 0; rg < 2; ++rg)
            #pragma unroll
            for (int cg = 0; cg < 2; ++cg) S[rg][cg] = (f32x4){0.f, 0.f, 0.f, 0.f};
        LOADK(kA, 0);
        LOADK(kB, 4);  USEK(kA, 0);
        LOADK(kA, 8);  USEK(kB, 4);
        LOADK(kB, 12); USEK(kA, 8);
        LOADK(kA, 16); USEK(kB, 12);
        LOADK(kB, 20); USEK(kA, 16);
        LOADK(kA, 24); USEK(kB, 20);
        LOADK(kB, 28); USEK(kA, 24);
                       USEK(kB, 28);
    };

    f32x4 O[2][8];
    #pragma unroll
    for (int rg = 0; rg < 2; ++rg)
        #pragma unroll
        for (int fn = 0; fn < 8; ++fn) O[rg][fn] = (f32x4){0.f, 0.f, 0.f, 0.f};
    float mq[8];
    #pragma unroll
    for (int u = 0; u < 8; ++u) mq[u] = -INFINITY;
    float m2a = -INFINITY, m2b = -INFINITY, l2a = 0.f, l2b = 0.f;

    f16x8 vA[8], vB[8];
    auto LOADV = [&](f16x8* buf, int ks2) {
        #pragma unroll
        for (int fn = 0; fn < 8; ++fn)
            buf[fn] = *(const f16x8*)(vp[fn] + ks2 * 32);
    };
    float ba[8], bb[8];
    auto USEV = [&](const f16x8* vb2, int ks2) {
        f16 ba16 = (f16)ba[ks2], bb16 = (f16)bb[ks2];
        f16x8 pa0 = *(const f16x8*)(pr0 + ks2 * 2048);
        f16x8 pa1 = *(const f16x8*)(pr1 + ks2 * 2048);
        #pragma unroll
        for (int j = 0; j < 8; ++j) { pa0[j] *= ba16; pa1[j] *= bb16; }
        __builtin_amdgcn_s_setprio(1);
        #pragma unroll
        for (int fn = 0; fn < 8; ++fn) {
            O[0][fn] = mfma16(pa0, vb2[fn], O[0][fn]);
            O[1][fn] = mfma16(pa1, vb2[fn], O[1][fn]);
        }
        __builtin_amdgcn_s_setprio(0);
    };

    QK();   // tile 0

    for (int it = 0; it < ITERS; ++it) {
        // ---- strip softmax: max, exp, sum over own 32 cols; publish P + {m,s} ----
        #pragma unroll
        for (int rg = 0; rg < 2; ++rg)
            #pragma unroll
            for (int i = 0; i < 4; ++i) {
                float a = S[rg][0][i], b = S[rg][1][i];
                float mx = fmaxf(a, b);
                mx = fmaxf(mx, __shfl_xor(mx, 1));
                mx = fmaxf(mx, __shfl_xor(mx, 2));
                mx = fmaxf(mx, __shfl_xor(mx, 4));
                mx = fmaxf(mx, __shfl_xor(mx, 8));
                float p0 = __expf(a - mx), p1 = __expf(b - mx);
                float s = p0 + p1;
                s += __shfl_xor(s, 1);
                s += __shfl_xor(s, 2);
                s += __shfl_xor(s, 4);
                s += __shfl_xor(s, 8);
                int m = rg * 16 + lg * 4 + i;
                int off0 = wave * 2048 + m * 64 + ((l15 >> 3) << 4) + ((l15 & 7) << 1);
                *(f16*)((char*)Pl + off0)      = (f16)p0;
                *(f16*)((char*)Pl + off0 + 32) = (f16)p1;
                if (l15 == 0) red[m][wave] = make_float2(mx, s);
            }
        __syncthreads();

        // ---- V prefetch immediately: combine-VALU below covers the latency ----
        LOADV(vA, 0);
        LOADV(vB, 1);

        // ---- combine: global row max, beta per strip, l update ----
        float M2an = m2a, M2bn = m2b;
        #pragma unroll
        for (int s2 = 0; s2 < 8; ++s2) {
            M2an = fmaxf(M2an, red[l15][s2].x);
            M2bn = fmaxf(M2bn, red[l15 + 16][s2].x);
        }
        float laa = 0.f, lbb = 0.f;
        #pragma unroll
        for (int s2 = 0; s2 < 8; ++s2) {
            float2 ra = red[l15][s2], rb = red[l15 + 16][s2];
            ba[s2] = __expf(ra.x - M2an); laa += ra.y * ba[s2];
            bb[s2] = __expf(rb.x - M2bn); lbb += rb.y * bb[s2];
        }
        l2a = l2a * __expf(m2a - M2an) + laa; m2a = M2an;
        l2b = l2b * __expf(m2b - M2bn) + lbb; m2b = M2bn;

        // ---- q-view alpha via shfl; rescale O ----
        float al[2][4];
        #pragma unroll
        for (int rg = 0; rg < 2; ++rg)
            #pragma unroll
            for (int i = 0; i < 4; ++i) {
                int u = rg * 4 + i;
                int src = (lane & 48) | (lg * 4 + i);
                float Mq = __shfl(rg ? M2bn : M2an, src);
                al[rg][i] = __expf(mq[u] - Mq);
                mq[u] = Mq;
            }
        #pragma unroll
        for (int rg = 0; rg < 2; ++rg)
            #pragma unroll
            for (int fn = 0; fn < 8; ++fn)
                #pragma unroll
                for (int i = 0; i < 4; ++i)
                    O[rg][fn][i] *= al[rg][i];

        // ---- PV with double-buffered V registers ----
        // USEV(x,k) consumes the tile loaded into x two steps earlier;
        // LOADV(x,k+2) refills the buffer just consumed.
        USEV(vA, 0);  LOADV(vA, 2);
        USEV(vB, 1);  LOADV(vB, 3);
        USEV(vA, 2);  LOADV(vA, 4);
        USEV(vB, 3);  LOADV(vB, 5);
        USEV(vA, 4);  LOADV(vA, 6);
        USEV(vB, 5);  LOADV(vB, 7);
        USEV(vA, 6);
        USEV(vB, 7);

        // ---- advance, then next tile's QK before the closing barrier ----
        kp0 += (size_t)BN * D_;
        kp1 += (size_t)BN * D_;
        #pragma unroll
        for (int fn = 0; fn < 8; ++fn) vp[fn] += BN;
        if (it + 1 < ITERS) QK();
        __syncthreads();
    }

    // ---- epilogue: unnormalized O + per-row m/l partials ----
    float* Op = Opart + (size_t)chunk * B_ * D_;
    #pragma unroll
    for (int rg = 0; rg < 2; ++rg)
        #pragma unroll
        for (int fn = 0; fn < 8; ++fn)
            #pragma unroll
            for (int i = 0; i < 4; ++i) {
                int row = b0 + rg * 16 + lg * 4 + i;
                int col = wave * DSLICE + fn * 16 + l15;
                Op[(size_t)row * D_ + col] = O[rg][fn][i];
            }
    if (wave == 0 && lg == 0) {
        Mpart[(size_t)chunk * B_ + b0 + l15]      = m2a;
        Lpart[(size_t)chunk * B_ + b0 + l15]      = l2a;
        Mpart[(size_t)chunk * B_ + b0 + 16 + l15] = m2b;
        Lpart[(size_t)chunk * B_ + b0 + 16 + l15] = l2b;
    }
}

// ---- combine NSPLIT=2 partials ----------------------------------------------
__global__ void combine_k(const float* __restrict__ Opart,
                          const float* __restrict__ Mp, const float* __restrict__ Lp,
                          float* __restrict__ Outg)
{
    int b = blockIdx.x;
    float m0 = Mp[b], m1 = Mp[B_ + b];
    float l0 = Lp[b], l1 = Lp[B_ + b];
    float M  = fmaxf(m0, m1);
    float w0 = __expf(m0 - M), w1 = __expf(m1 - M);
    float inv = 1.f / (w0 * l0 + w1 * l1);
    const float4* O0 = (const float4*)(Opart + (size_t)b * D_);
    const float4* O1 = (const float4*)(Opart + (size_t)B_ * D_ + (size_t)b * D_);
    float4* o = (float4*)(Outg + (size_t)b * D_);
    for (int i = threadIdx.x; i < D_ / 4; i += blockDim.x) {
        float4 a = O0[i], c = O1[i];
        float4 r;
        r.x = (w0 * a.x + w1 * c.x) * inv;
        r.y = (w0 * a.y + w1 * c.y) * inv;
        r.z = (w0 * a.z + w1 * c.z) * inv;
        r.w = (w0 * a.w + w1 * c.w) * inv;
        o[i] = r;
    }
}

extern "C" void kernel_launch(void* const* d_in, const int* in_sizes, int n_in,
                              void* d_out, int out_size, void* d_ws, size_t ws_size,
                              hipStream_t stream) {
    const float* X = (const float*)d_in[0];
    const float* K = (const float*)d_in[1];
    const float* V = (const float*)d_in[2];
    float* Out = (float*)d_out;

    const size_t szKh = (size_t)N_ * D_ * sizeof(f16);   // 64 MiB
    const size_t szVT = (size_t)N_ * D_ * sizeof(f16);   // 64 MiB
    const size_t szOp = 2ull * B_ * D_ * sizeof(float);  // 32 MiB
    const size_t szM  = 2ull * B_ * sizeof(float);

    f16*   Kh = (f16*)d_ws;
    f16*   VT = (f16*)((char*)d_ws + szKh);
    float* Op = (float*)((char*)d_ws + szKh + szVT);
    float* Mp = (float*)((char*)Op + szOp);
    float* Lp = (float*)((char*)Mp + szM);

    conv_k16<<<(N_ * D_ / 8) / 256, 256, 0, stream>>>(K, Kh);
    conv_vt<<<dim3(N_ / 64, D_ / 64), 256, 0, stream>>>(V, VT);
    attn_main<<<256, THREADS, 0, stream>>>(X, Kh, VT, Op, Mp, Lp);
    combine_k<<<B_, 256, 0, stream>>>(Op, Mp, Lp, Out);
}